// Round 7
// baseline (240.980 us; speedup 1.0000x reference)
//
#include <hip/hip_runtime.h>
#include <hip/hip_bf16.h>
#include <math.h>

// Problem constants (CrossAttention_14955076125227)
//   B=4, N=2048, M=2048, Dq=512, Dc=768, H=8, Dh=64, inner=512
#define BB 4
#define NN 2048
#define MM 2048
#define DQ 512
#define DC 768
#define NH 8
#define DH 64
#define INNER 512
#define KVS 1024   // fused K|V row stride (bf16 elems)

typedef short bf16x8 __attribute__((ext_vector_type(8)));
typedef short bf16x4 __attribute__((ext_vector_type(4)));
typedef float f32x4  __attribute__((ext_vector_type(4)));

__device__ inline short fbf(float f) {
    __hip_bfloat16 h = __float2bfloat16(f);
    return __builtin_bit_cast(short, h);
}

// async global->LDS, 16 B per lane. LDS dest is wave-uniform base; HW adds lane*16.
__device__ inline void gld16(const void* gptr, void* lds_uniform_base) {
    __builtin_amdgcn_global_load_lds(
        (const __attribute__((address_space(1))) void*)gptr,
        (__attribute__((address_space(3))) void*)lds_uniform_base, 16, 0, 0);
}

// ---------------------------------------------------------------------------
// Fused LayerNorm pair -> bf16. grid (R, 2): y=0 -> x (D=512), y=1 -> cond (768)
// ---------------------------------------------------------------------------
__global__ __launch_bounds__(256) void ln2_bf16(
    const float* __restrict__ x, const float* __restrict__ cond,
    const float* __restrict__ gx, const float* __restrict__ bx,
    const float* __restrict__ gc, const float* __restrict__ bc,
    short* __restrict__ xn, short* __restrict__ cn)
{
    const int which = blockIdx.y;
    const float* in = which ? cond : x;
    const float* g  = which ? gc : gx;
    const float* bb = which ? bc : bx;
    short* out      = which ? cn : xn;
    const int D     = which ? DC : DQ;

    const int row = blockIdx.x;
    const float* xr = in + (size_t)row * D;
    float s = 0.f, s2 = 0.f;
    for (int d = threadIdx.x; d < D; d += 256) {
        float v = xr[d];
        s += v; s2 += v * v;
    }
    __shared__ float red[2][4];
    #pragma unroll
    for (int off = 32; off; off >>= 1) {
        s  += __shfl_down(s,  off, 64);
        s2 += __shfl_down(s2, off, 64);
    }
    const int wave = threadIdx.x >> 6, lane = threadIdx.x & 63;
    if (lane == 0) { red[0][wave] = s; red[1][wave] = s2; }
    __syncthreads();
    if (threadIdx.x == 0) {
        float ts = red[0][0] + red[0][1] + red[0][2] + red[0][3];
        float t2 = red[1][0] + red[1][1] + red[1][2] + red[1][3];
        float mu = ts / (float)D;
        float var = t2 / (float)D - mu * mu;
        red[0][0] = mu;
        red[1][0] = rsqrtf(var + 1e-5f);
    }
    __syncthreads();
    const float mu = red[0][0], rstd = red[1][0];
    short* o = out + (size_t)row * D;
    for (int d = threadIdx.x; d < D; d += 256)
        o[d] = fbf((xr[d] - mu) * rstd * g[d] + bb[d]);
}

// ---------------------------------------------------------------------------
// Final LayerNorm with fused residual: out = LN(bf16(ob) + x), D=512.
// ---------------------------------------------------------------------------
__global__ __launch_bounds__(256) void layernorm_res_f32(
    const short* __restrict__ ob, const float* __restrict__ x,
    const float* __restrict__ g, const float* __restrict__ b,
    float* __restrict__ out)
{
    const int row = blockIdx.x;
    const int t = threadIdx.x;
    const size_t base = (size_t)row * DQ;
    float v0, v1;
    {
        unsigned u0 = (unsigned)(unsigned short)ob[base + t];
        unsigned u1 = (unsigned)(unsigned short)ob[base + t + 256];
        v0 = __builtin_bit_cast(float, u0 << 16) + x[base + t];
        v1 = __builtin_bit_cast(float, u1 << 16) + x[base + t + 256];
    }
    float s = v0 + v1, s2 = v0 * v0 + v1 * v1;
    __shared__ float red[2][4];
    #pragma unroll
    for (int off = 32; off; off >>= 1) {
        s  += __shfl_down(s,  off, 64);
        s2 += __shfl_down(s2, off, 64);
    }
    const int wave = t >> 6, lane = t & 63;
    if (lane == 0) { red[0][wave] = s; red[1][wave] = s2; }
    __syncthreads();
    if (t == 0) {
        float ts = red[0][0] + red[0][1] + red[0][2] + red[0][3];
        float t2 = red[1][0] + red[1][1] + red[1][2] + red[1][3];
        float mu = ts / (float)DQ;
        float var = t2 / (float)DQ - mu * mu;
        red[0][0] = mu;
        red[1][0] = rsqrtf(var + 1e-5f);
    }
    __syncthreads();
    const float mu = red[0][0], rstd = red[1][0];
    out[base + t]       = (v0 - mu) * rstd * g[t]       + b[t];
    out[base + t + 256] = (v1 - mu) * rstd * g[t + 256] + b[t + 256];
}

// ---------------------------------------------------------------------------
// Fused transpose+cvt of all 4 weights. grid (16, 80).
// ---------------------------------------------------------------------------
__global__ __launch_bounds__(256) void transpose4(
    const float* __restrict__ Wq, const float* __restrict__ Wk,
    const float* __restrict__ Wv, const float* __restrict__ Wo,
    short* __restrict__ Wqt, short* __restrict__ Wkvt, short* __restrict__ Wot)
{
    const int y = blockIdx.y;
    const float* W; short* Wt; int K, k0;
    if (y < 16)      { W = Wq; Wt = Wqt;  K = DQ; k0 = y * 32; }
    else if (y < 40) { W = Wk; Wt = Wkvt; K = DC; k0 = (y - 16) * 32; }
    else if (y < 64) { W = Wv; Wt = Wkvt + (size_t)512 * DC; K = DC; k0 = (y - 40) * 32; }
    else             { W = Wo; Wt = Wot;  K = DQ; k0 = (y - 64) * 32; }

    __shared__ float tile[32][33];
    const int t = threadIdx.x;
    const int n0 = blockIdx.x * 32;
    const int r = t >> 3, c4 = (t & 7) * 4;
    float4 vv = *(const float4*)&W[(size_t)(k0 + r) * 512 + n0 + c4];
    tile[c4 + 0][r] = vv.x; tile[c4 + 1][r] = vv.y;
    tile[c4 + 2][r] = vv.z; tile[c4 + 3][r] = vv.w;
    __syncthreads();
    short4 s;
    s.x = fbf(tile[r][c4 + 0]); s.y = fbf(tile[r][c4 + 1]);
    s.z = fbf(tile[r][c4 + 2]); s.w = fbf(tile[r][c4 + 3]);
    *(short4*)&Wt[(size_t)(n0 + r) * K + k0 + c4] = s;
}

// ---------------------------------------------------------------------------
// Fused q+kv projection GEMM. grid (12, 64):
//  x<4 : q = (xn @ Wq)*qsc, Nout=512, K=512
//  x>=4: kv = cn @ [Wk|Wv], Nout=1024, K=768
// ---------------------------------------------------------------------------
#define GBK 32

__global__ __launch_bounds__(256) void qkv_gemm(
    const short* __restrict__ xn, const short* __restrict__ cn,
    const short* __restrict__ Wqt, const short* __restrict__ Wkvt,
    short* __restrict__ qb, short* __restrict__ kvb, float qsc)
{
    const short* A; const short* Bt; short* outp; int K, Nout, n0; float sc;
    if (blockIdx.x < 4) {
        A = xn; Bt = Wqt; outp = qb; K = DQ; Nout = 512;
        n0 = blockIdx.x * 128; sc = qsc;
    } else {
        A = cn; Bt = Wkvt; outp = kvb; K = DC; Nout = 1024;
        n0 = (blockIdx.x - 4) * 128; sc = 1.f;
    }
    __shared__ short As[128 * GBK];
    __shared__ short Bs[128 * GBK];
    const int t = threadIdx.x;
    const int w = t >> 6, lane = t & 63;
    const int quad = lane >> 4, l16 = lane & 15;
    const int m0 = blockIdx.y * 128;
    const int wm = (w >> 1) * 64, wn = (w & 1) * 64;

    f32x4 acc[4][4];
    #pragma unroll
    for (int i = 0; i < 4; ++i)
        #pragma unroll
        for (int j = 0; j < 4; ++j) acc[i][j] = (f32x4){0.f, 0.f, 0.f, 0.f};

    for (int kt = 0; kt < K; kt += GBK) {
        __syncthreads();
        #pragma unroll
        for (int i = 0; i < 2; ++i) {
            const int j = w * 2 + i;
            const int c = j * 64 + lane;
            gld16(&A[(size_t)(m0 + (c >> 2)) * K + kt + (c & 3) * 8],
                  (char*)As + j * 1024);
            gld16(&Bt[(size_t)(n0 + (c >> 2)) * K + kt + (c & 3) * 8],
                  (char*)Bs + j * 1024);
        }
        __syncthreads();

        bf16x8 af[4], bfr[4];
        #pragma unroll
        for (int mt = 0; mt < 4; ++mt)
            af[mt] = *(bf16x8*)&As[(wm + mt * 16 + l16) * GBK + quad * 8];
        #pragma unroll
        for (int nt = 0; nt < 4; ++nt)
            bfr[nt] = *(bf16x8*)&Bs[(wn + nt * 16 + l16) * GBK + quad * 8];
        #pragma unroll
        for (int mt = 0; mt < 4; ++mt)
            #pragma unroll
            for (int nt = 0; nt < 4; ++nt)
                acc[mt][nt] = __builtin_amdgcn_mfma_f32_16x16x32_bf16(
                    af[mt], bfr[nt], acc[mt][nt], 0, 0, 0);
    }

    #pragma unroll
    for (int mt = 0; mt < 4; ++mt)
        #pragma unroll
        for (int r = 0; r < 4; ++r) {
            const int m = m0 + wm + mt * 16 + quad * 4 + r;
            #pragma unroll
            for (int nt = 0; nt < 4; ++nt) {
                const int n = n0 + wn + nt * 16 + l16;
                outp[(size_t)m * Nout + n] = fbf(acc[mt][nt][r] * sc);
            }
        }
}

// ---------------------------------------------------------------------------
// o-proj GEMM: C = ab @ Wot^T + bias, bf16 out. Tile 128x64.
// ---------------------------------------------------------------------------
__global__ __launch_bounds__(256) void oproj_gemm(
    const short* __restrict__ A, const short* __restrict__ Bt,
    short* __restrict__ outb, const float* __restrict__ bias)
{
    const int K = INNER, Nout = INNER;
    __shared__ short As[128 * GBK];
    __shared__ short Bs[64 * GBK];
    const int t = threadIdx.x;
    const int w = t >> 6, lane = t & 63;
    const int quad = lane >> 4, l16 = lane & 15;
    const int m0 = blockIdx.y * 128, n0 = blockIdx.x * 64;
    const int wm = (w >> 1) * 64, wn = (w & 1) * 32;

    f32x4 acc[4][2];
    #pragma unroll
    for (int i = 0; i < 4; ++i)
        #pragma unroll
        for (int j = 0; j < 2; ++j) acc[i][j] = (f32x4){0.f, 0.f, 0.f, 0.f};

    for (int kt = 0; kt < K; kt += GBK) {
        __syncthreads();
        #pragma unroll
        for (int i = 0; i < 2; ++i) {
            const int j = w * 2 + i;
            const int c = j * 64 + lane;
            gld16(&A[(size_t)(m0 + (c >> 2)) * K + kt + (c & 3) * 8],
                  (char*)As + j * 1024);
        }
        {
            const int c = w * 64 + lane;
            gld16(&Bt[(size_t)(n0 + (c >> 2)) * K + kt + (c & 3) * 8],
                  (char*)Bs + w * 1024);
        }
        __syncthreads();

        bf16x8 af[4], bfr[2];
        #pragma unroll
        for (int mt = 0; mt < 4; ++mt)
            af[mt] = *(bf16x8*)&As[(wm + mt * 16 + l16) * GBK + quad * 8];
        #pragma unroll
        for (int nt = 0; nt < 2; ++nt)
            bfr[nt] = *(bf16x8*)&Bs[(wn + nt * 16 + l16) * GBK + quad * 8];
        #pragma unroll
        for (int mt = 0; mt < 4; ++mt)
            #pragma unroll
            for (int nt = 0; nt < 2; ++nt)
                acc[mt][nt] = __builtin_amdgcn_mfma_f32_16x16x32_bf16(
                    af[mt], bfr[nt], acc[mt][nt], 0, 0, 0);
    }

    #pragma unroll
    for (int mt = 0; mt < 4; ++mt)
        #pragma unroll
        for (int r = 0; r < 4; ++r) {
            const int m = m0 + wm + mt * 16 + quad * 4 + r;
            #pragma unroll
            for (int nt = 0; nt < 2; ++nt) {
                const int n = n0 + wn + nt * 16 + l16;
                outb[(size_t)m * Nout + n] = fbf(acc[mt][nt][r] + bias[n]);
            }
        }
}

// ---------------------------------------------------------------------------
// bf16-MFMA flash attention v5: S^T form, no-max softmax, j-split, and
// REGISTER-DIRECT P: the S^T C-layout (col i=l16, rows j=quad*4+r) is exactly
// the A-operand layout of v_mfma_f32_16x16x16_bf16 (A[m=l16][k=quad*4+idx]),
// so P feeds PV straight from registers -- no LDS round-trip, no Ps buffer.
// PV B-frags: ds_read_b64 from V^T; l-sum via constant ones B-frag (no LDS).
// K/V double-buffered (one barrier/iter, staging overlaps compute).
// Block = 512 thr = 8 waves: waves 0-3 j in [0,1024), 4-7 j in [1024,2048),
// same 128 Q rows; O,l additive -> one-time LDS combine.
// q PRE-SCALED by 0.125*log2(e) (p = exp2(s)).
// ---------------------------------------------------------------------------
#define QT 128
#define JT 64
#define KSTR 72      // 144 B rows: 16B-aligned for b128
#define MH (MM / 2)  // 1024 j's per wave-group
#define NIT (MH / JT)

__global__ __launch_bounds__(512) void attention_mfma(
    const short* __restrict__ q, const short* __restrict__ kv,
    short* __restrict__ o)
{
    const int b = blockIdx.z, h = blockIdx.y;
    const int i0 = blockIdx.x * QT;
    const int t = threadIdx.x;
    const int wave = t >> 6, lane = t & 63;
    const int w4 = wave & 3, hh = wave >> 2;   // row-group, j-half
    const int quad = lane >> 4, l16 = lane & 15;

    // LDS: double-buffered K/V tiles; combine buffers overlay afterwards.
    __shared__ __align__(16) char smem[73728];
    typedef short KT[2][64][KSTR];                       // [half][row][col]
    KT* Ks = (KT*)smem;                                  // Ks[buf]: 18432 B each
    KT* Vt = (KT*)(smem + 36864);                        // Vt[buf]
    float (*Obuf)[32][68] = (float(*)[32][68])(smem);    // 34816 B (overlay)
    float (*Lbuf)[32]     = (float(*)[32])(smem + 34816);

    // Q fragments (B operand of QK): col i = l16, k = cc*32 + quad*8
    bf16x8 qf[2][2];
    #pragma unroll
    for (int it = 0; it < 2; ++it) {
        const int row = i0 + w4 * 32 + it * 16 + l16;
        const short* qp = &q[((size_t)(b * NN + row)) * INNER + h * DH];
        qf[it][0] = *(const bf16x8*)&qp[quad * 8];
        qf[it][1] = *(const bf16x8*)&qp[32 + quad * 8];
    }

    f32x4 Oa[2][4];   // [it][dt]: O rows quad*4+r, col dt*16+l16 (unnormalized)
    f32x4 La[2];      // [it]: l rows quad*4+r (identical across l16 lanes)
    #pragma unroll
    for (int it = 0; it < 2; ++it) {
        La[it] = (f32x4){0.f, 0.f, 0.f, 0.f};
        #pragma unroll
        for (int dt = 0; dt < 4; ++dt) Oa[it][dt] = (f32x4){0.f, 0.f, 0.f, 0.f};
    }

    const bf16x4 ones4 = {(short)0x3F80, (short)0x3F80, (short)0x3F80, (short)0x3F80};

    // staging: threads 0-255 stage j-half 0, 256-511 half 1
    const int tt = t & 255, th = t >> 8;
    const int kjj = tt >> 3, kdq = (tt & 7) * 8;   // K: 32 rows x 8 chunks, x2
    const int vjp = tt & 31, vd0 = (tt >> 5) * 8;  // V: j-pair, 8 d each

    auto stage = [&](int pb, int jj0n) {
        const int j0g = th * MH + jj0n;
        #pragma unroll
        for (int ii = 0; ii < 2; ++ii) {
            const int jj = ii * 32 + kjj;
            *(bf16x8*)&Ks[pb][th][jj][kdq] =
                *(const bf16x8*)&kv[((size_t)(b * MM + j0g + jj)) * KVS + h * DH + kdq];
        }
        const int jg = j0g + 2 * vjp;
        bf16x8 va = *(const bf16x8*)&kv[((size_t)(b * MM + jg))     * KVS + 512 + h * DH + vd0];
        bf16x8 vb = *(const bf16x8*)&kv[((size_t)(b * MM + jg + 1)) * KVS + 512 + h * DH + vd0];
        #pragma unroll
        for (int i = 0; i < 8; ++i) {
            short2 pr; pr.x = va[i]; pr.y = vb[i];
            *(short2*)&Vt[pb][th][vd0 + i][2 * vjp] = pr;
        }
    };

    stage(0, 0);
    __syncthreads();

    for (int itr = 0; itr < NIT; ++itr) {
        const int p = itr & 1;
        if (itr + 1 < NIT) stage(p ^ 1, (itr + 1) * JT);

        #pragma unroll
        for (int jt = 0; jt < 4; ++jt) {
            // K-frags for this 16-j tile (shared across both i-tiles)
            bf16x8 kb0 = *(bf16x8*)&Ks[p][hh][jt * 16 + l16][quad * 8];
            bf16x8 kb1 = *(bf16x8*)&Ks[p][hh][jt * 16 + l16][32 + quad * 8];

            // S^T = K Q^T ; p = exp2(s); pack into PV A-frags (register-direct)
            bf16x4 pf[2];
            #pragma unroll
            for (int it = 0; it < 2; ++it) {
                f32x4 c = (f32x4){0.f, 0.f, 0.f, 0.f};
                c = __builtin_amdgcn_mfma_f32_16x16x32_bf16(kb0, qf[it][0], c, 0, 0, 0);
                c = __builtin_amdgcn_mfma_f32_16x16x32_bf16(kb1, qf[it][1], c, 0, 0, 0);
                const float e0 = exp2f(c[0]), e1 = exp2f(c[1]);
                const float e2 = exp2f(c[2]), e3 = exp2f(c[3]);
                uint2 pk;   // low short = r0 (truncation-pack)
                pk.x = __builtin_amdgcn_perm(__builtin_bit_cast(unsigned, e1),
                                             __builtin_bit_cast(unsigned, e0), 0x07060302u);
                pk.y = __builtin_amdgcn_perm(__builtin_bit_cast(unsigned, e3),
                                             __builtin_bit_cast(unsigned, e2), 0x07060302u);
                pf[it] = __builtin_bit_cast(bf16x4, pk);
            }

            // O += P V  (B-frag: V^T[d=dt*16+l16][j=jt*16+quad*4 ..+3], b64)
            #pragma unroll
            for (int dt = 0; dt < 4; ++dt) {
                bf16x4 vb4 = *(bf16x4*)&Vt[p][hh][dt * 16 + l16][jt * 16 + quad * 4];
                Oa[0][dt] = __builtin_amdgcn_mfma_f32_16x16x16bf16_1k(
                    pf[0], vb4, Oa[0][dt], 0, 0, 0);
                Oa[1][dt] = __builtin_amdgcn_mfma_f32_16x16x16bf16_1k(
                    pf[1], vb4, Oa[1][dt], 0, 0, 0);
            }
            // l += P . 1 (constant ones B-frag, no LDS)
            La[0] = __builtin_amdgcn_mfma_f32_16x16x16bf16_1k(pf[0], ones4, La[0], 0, 0, 0);
            La[1] = __builtin_amdgcn_mfma_f32_16x16x16bf16_1k(pf[1], ones4, La[1], 0, 0, 0);
        }
        __syncthreads();
    }

    // ---- combine the two j-halves (O, l additive) via LDS ----
    if (wave >= 4) {
        #pragma unroll
        for (int it = 0; it < 2; ++it) {
            #pragma unroll
            for (int r = 0; r < 4; ++r) {
                const int qr = it * 16 + quad * 4 + r;
                #pragma unroll
                for (int dt = 0; dt < 4; ++dt)
                    Obuf[w4][qr][dt * 16 + l16] = Oa[it][dt][r];
                if (l16 == 0) Lbuf[w4][qr] = La[it][r];
            }
        }
    }
    __syncthreads();
    if (wave < 4) {
        #pragma unroll
        for (int it = 0; it < 2; ++it) {
            #pragma unroll
            for (int r = 0; r < 4; ++r) {
                const int qr = it * 16 + quad * 4 + r;
                const float ltot = La[it][r] + Lbuf[w4][qr];  // all l16 lanes identical
                const float inv = 1.f / ltot;
                const int row = i0 + w4 * 32 + qr;
                #pragma unroll
                for (int dt = 0; dt < 4; ++dt) {
                    const float val = Oa[it][dt][r] + Obuf[w4][qr][dt * 16 + l16];
                    o[((size_t)(b * NN + row)) * INNER + h * DH + dt * 16 + l16] =
                        fbf(val * inv);
                }
            }
        }
    }
}

// ---------------------------------------------------------------------------
// Launch
// ---------------------------------------------------------------------------
extern "C" void kernel_launch(void* const* d_in, const int* in_sizes, int n_in,
                              void* d_out, int out_size, void* d_ws, size_t ws_size,
                              hipStream_t stream)
{
    const float* x     = (const float*)d_in[0];
    const float* cond  = (const float*)d_in[1];
    const float* lnx_g = (const float*)d_in[2];
    const float* lnx_b = (const float*)d_in[3];
    const float* lnc_g = (const float*)d_in[4];
    const float* lnc_b = (const float*)d_in[5];
    const float* Wq    = (const float*)d_in[6];
    const float* Wk    = (const float*)d_in[7];
    const float* Wv    = (const float*)d_in[8];
    const float* Wo    = (const float*)d_in[9];
    const float* bo    = (const float*)d_in[10];
    const float* lnf_g = (const float*)d_in[11];
    const float* lnf_b = (const float*)d_in[12];
    float* out = (float*)d_out;
    char* ws = (char*)d_ws;

    const int R = BB * NN;  // 8192

    // workspace layout (bytes, 16B-aligned)
    short* xn_bf  = (short*)(ws);                    //  8 MB
    short* cn_bf  = (short*)(ws + (8u << 20));       // 12 MB
    short* Wq_t   = (short*)(ws + (20u << 20));      // 0.5 MB
    short* Wo_t   = (short*)(ws + (21u << 20));      // 0.5 MB
    short* Wkv_t  = (short*)(ws + (22u << 20));      // 1.5 MB
    short* qb     = (short*)(ws + (24u << 20));      //  8 MB
    short* kvb    = (short*)(ws + (32u << 20));      // 16 MB
    short* ab     = (short*)(ws + (48u << 20));      //  8 MB
    short* ob     = (short*)(ws + (56u << 20));      //  8 MB

    transpose4<<<dim3(16, 80), 256, 0, stream>>>(Wq, Wk, Wv, Wo, Wq_t, Wkv_t, Wo_t);

    ln2_bf16<<<dim3(R, 2), 256, 0, stream>>>(
        x, cond, lnx_g, lnx_b, lnc_g, lnc_b, xn_bf, cn_bf);

    // q = (xn @ Wq)*0.125*log2e ; [k|v] = cn @ [Wk|Wv]
    qkv_gemm<<<dim3(12, R / 128), 256, 0, stream>>>(
        xn_bf, cn_bf, Wq_t, Wkv_t, qb, kvb, 0.125f * 1.44269504089f);

    attention_mfma<<<dim3(NN / QT, NH, BB), 512, 0, stream>>>(qb, kvb, ab);

    // o-proj: bf16 out + bias (residual folded into the final LN)
    oproj_gemm<<<dim3(INNER / 64, R / 128), 256, 0, stream>>>(ab, Wo_t, ob, bo);

    layernorm_res_f32<<<R, 256, 0, stream>>>(ob, x, lnf_g, lnf_b, out);
}

// Round 8
// 237.737 us; speedup vs baseline: 1.0136x; 1.0136x over previous
//
#include <hip/hip_runtime.h>
#include <hip/hip_bf16.h>
#include <math.h>

// Problem constants (CrossAttention_14955076125227)
//   B=4, N=2048, M=2048, Dq=512, Dc=768, H=8, Dh=64, inner=512
#define BB 4
#define NN 2048
#define MM 2048
#define DQ 512
#define DC 768
#define NH 8
#define DH 64
#define INNER 512
#define KVS 1024   // fused K|V row stride (bf16 elems)

typedef short bf16x8 __attribute__((ext_vector_type(8)));
typedef short bf16x4 __attribute__((ext_vector_type(4)));
typedef float f32x4  __attribute__((ext_vector_type(4)));

__device__ inline short fbf(float f) {
    __hip_bfloat16 h = __float2bfloat16(f);
    return __builtin_bit_cast(short, h);
}

// async global->LDS, 16 B per lane. LDS dest is wave-uniform base; HW adds lane*16.
__device__ inline void gld16(const void* gptr, void* lds_uniform_base) {
    __builtin_amdgcn_global_load_lds(
        (const __attribute__((address_space(1))) void*)gptr,
        (__attribute__((address_space(3))) void*)lds_uniform_base, 16, 0, 0);
}

// ---------------------------------------------------------------------------
// Fused LayerNorm pair -> bf16. grid (R, 2): y=0 -> x (D=512), y=1 -> cond (768)
// ---------------------------------------------------------------------------
__global__ __launch_bounds__(256) void ln2_bf16(
    const float* __restrict__ x, const float* __restrict__ cond,
    const float* __restrict__ gx, const float* __restrict__ bx,
    const float* __restrict__ gc, const float* __restrict__ bc,
    short* __restrict__ xn, short* __restrict__ cn)
{
    const int which = blockIdx.y;
    const float* in = which ? cond : x;
    const float* g  = which ? gc : gx;
    const float* bb = which ? bc : bx;
    short* out      = which ? cn : xn;
    const int D     = which ? DC : DQ;

    const int row = blockIdx.x;
    const float* xr = in + (size_t)row * D;
    float s = 0.f, s2 = 0.f;
    for (int d = threadIdx.x; d < D; d += 256) {
        float v = xr[d];
        s += v; s2 += v * v;
    }
    __shared__ float red[2][4];
    #pragma unroll
    for (int off = 32; off; off >>= 1) {
        s  += __shfl_down(s,  off, 64);
        s2 += __shfl_down(s2, off, 64);
    }
    const int wave = threadIdx.x >> 6, lane = threadIdx.x & 63;
    if (lane == 0) { red[0][wave] = s; red[1][wave] = s2; }
    __syncthreads();
    if (threadIdx.x == 0) {
        float ts = red[0][0] + red[0][1] + red[0][2] + red[0][3];
        float t2 = red[1][0] + red[1][1] + red[1][2] + red[1][3];
        float mu = ts / (float)D;
        float var = t2 / (float)D - mu * mu;
        red[0][0] = mu;
        red[1][0] = rsqrtf(var + 1e-5f);
    }
    __syncthreads();
    const float mu = red[0][0], rstd = red[1][0];
    short* o = out + (size_t)row * D;
    for (int d = threadIdx.x; d < D; d += 256)
        o[d] = fbf((xr[d] - mu) * rstd * g[d] + bb[d]);
}

// ---------------------------------------------------------------------------
// Final LayerNorm with fused residual: out = LN(bf16(ob) + x), D=512.
// ---------------------------------------------------------------------------
__global__ __launch_bounds__(256) void layernorm_res_f32(
    const short* __restrict__ ob, const float* __restrict__ x,
    const float* __restrict__ g, const float* __restrict__ b,
    float* __restrict__ out)
{
    const int row = blockIdx.x;
    const int t = threadIdx.x;
    const size_t base = (size_t)row * DQ;
    float v0, v1;
    {
        unsigned u0 = (unsigned)(unsigned short)ob[base + t];
        unsigned u1 = (unsigned)(unsigned short)ob[base + t + 256];
        v0 = __builtin_bit_cast(float, u0 << 16) + x[base + t];
        v1 = __builtin_bit_cast(float, u1 << 16) + x[base + t + 256];
    }
    float s = v0 + v1, s2 = v0 * v0 + v1 * v1;
    __shared__ float red[2][4];
    #pragma unroll
    for (int off = 32; off; off >>= 1) {
        s  += __shfl_down(s,  off, 64);
        s2 += __shfl_down(s2, off, 64);
    }
    const int wave = t >> 6, lane = t & 63;
    if (lane == 0) { red[0][wave] = s; red[1][wave] = s2; }
    __syncthreads();
    if (t == 0) {
        float ts = red[0][0] + red[0][1] + red[0][2] + red[0][3];
        float t2 = red[1][0] + red[1][1] + red[1][2] + red[1][3];
        float mu = ts / (float)DQ;
        float var = t2 / (float)DQ - mu * mu;
        red[0][0] = mu;
        red[1][0] = rsqrtf(var + 1e-5f);
    }
    __syncthreads();
    const float mu = red[0][0], rstd = red[1][0];
    out[base + t]       = (v0 - mu) * rstd * g[t]       + b[t];
    out[base + t + 256] = (v1 - mu) * rstd * g[t + 256] + b[t + 256];
}

// ---------------------------------------------------------------------------
// Fused transpose+cvt of all 4 weights. grid (16, 80).
// ---------------------------------------------------------------------------
__global__ __launch_bounds__(256) void transpose4(
    const float* __restrict__ Wq, const float* __restrict__ Wk,
    const float* __restrict__ Wv, const float* __restrict__ Wo,
    short* __restrict__ Wqt, short* __restrict__ Wkvt, short* __restrict__ Wot)
{
    const int y = blockIdx.y;
    const float* W; short* Wt; int K, k0;
    if (y < 16)      { W = Wq; Wt = Wqt;  K = DQ; k0 = y * 32; }
    else if (y < 40) { W = Wk; Wt = Wkvt; K = DC; k0 = (y - 16) * 32; }
    else if (y < 64) { W = Wv; Wt = Wkvt + (size_t)512 * DC; K = DC; k0 = (y - 40) * 32; }
    else             { W = Wo; Wt = Wot;  K = DQ; k0 = (y - 64) * 32; }

    __shared__ float tile[32][33];
    const int t = threadIdx.x;
    const int n0 = blockIdx.x * 32;
    const int r = t >> 3, c4 = (t & 7) * 4;
    float4 vv = *(const float4*)&W[(size_t)(k0 + r) * 512 + n0 + c4];
    tile[c4 + 0][r] = vv.x; tile[c4 + 1][r] = vv.y;
    tile[c4 + 2][r] = vv.z; tile[c4 + 3][r] = vv.w;
    __syncthreads();
    short4 s;
    s.x = fbf(tile[r][c4 + 0]); s.y = fbf(tile[r][c4 + 1]);
    s.z = fbf(tile[r][c4 + 2]); s.w = fbf(tile[r][c4 + 3]);
    *(short4*)&Wt[(size_t)(n0 + r) * K + k0 + c4] = s;
}

// ---------------------------------------------------------------------------
// Fused q+kv projection GEMM. grid (12, 64):
//  x<4 : q = (xn @ Wq)*qsc, Nout=512, K=512
//  x>=4: kv = cn @ [Wk|Wv], Nout=1024, K=768
// ---------------------------------------------------------------------------
#define GBK 32

__global__ __launch_bounds__(256) void qkv_gemm(
    const short* __restrict__ xn, const short* __restrict__ cn,
    const short* __restrict__ Wqt, const short* __restrict__ Wkvt,
    short* __restrict__ qb, short* __restrict__ kvb, float qsc)
{
    const short* A; const short* Bt; short* outp; int K, Nout, n0; float sc;
    if (blockIdx.x < 4) {
        A = xn; Bt = Wqt; outp = qb; K = DQ; Nout = 512;
        n0 = blockIdx.x * 128; sc = qsc;
    } else {
        A = cn; Bt = Wkvt; outp = kvb; K = DC; Nout = 1024;
        n0 = (blockIdx.x - 4) * 128; sc = 1.f;
    }
    __shared__ short As[128 * GBK];
    __shared__ short Bs[128 * GBK];
    const int t = threadIdx.x;
    const int w = t >> 6, lane = t & 63;
    const int quad = lane >> 4, l16 = lane & 15;
    const int m0 = blockIdx.y * 128;
    const int wm = (w >> 1) * 64, wn = (w & 1) * 64;

    f32x4 acc[4][4];
    #pragma unroll
    for (int i = 0; i < 4; ++i)
        #pragma unroll
        for (int j = 0; j < 4; ++j) acc[i][j] = (f32x4){0.f, 0.f, 0.f, 0.f};

    for (int kt = 0; kt < K; kt += GBK) {
        __syncthreads();
        #pragma unroll
        for (int i = 0; i < 2; ++i) {
            const int j = w * 2 + i;
            const int c = j * 64 + lane;
            gld16(&A[(size_t)(m0 + (c >> 2)) * K + kt + (c & 3) * 8],
                  (char*)As + j * 1024);
            gld16(&Bt[(size_t)(n0 + (c >> 2)) * K + kt + (c & 3) * 8],
                  (char*)Bs + j * 1024);
        }
        __syncthreads();

        bf16x8 af[4], bfr[4];
        #pragma unroll
        for (int mt = 0; mt < 4; ++mt)
            af[mt] = *(bf16x8*)&As[(wm + mt * 16 + l16) * GBK + quad * 8];
        #pragma unroll
        for (int nt = 0; nt < 4; ++nt)
            bfr[nt] = *(bf16x8*)&Bs[(wn + nt * 16 + l16) * GBK + quad * 8];
        #pragma unroll
        for (int mt = 0; mt < 4; ++mt)
            #pragma unroll
            for (int nt = 0; nt < 4; ++nt)
                acc[mt][nt] = __builtin_amdgcn_mfma_f32_16x16x32_bf16(
                    af[mt], bfr[nt], acc[mt][nt], 0, 0, 0);
    }

    #pragma unroll
    for (int mt = 0; mt < 4; ++mt)
        #pragma unroll
        for (int r = 0; r < 4; ++r) {
            const int m = m0 + wm + mt * 16 + quad * 4 + r;
            #pragma unroll
            for (int nt = 0; nt < 4; ++nt) {
                const int n = n0 + wn + nt * 16 + l16;
                outp[(size_t)m * Nout + n] = fbf(acc[mt][nt][r] * sc);
            }
        }
}

// ---------------------------------------------------------------------------
// o-proj GEMM: C = ab @ Wot^T + bias, bf16 out. Tile 128x64.
// ---------------------------------------------------------------------------
__global__ __launch_bounds__(256) void oproj_gemm(
    const short* __restrict__ A, const short* __restrict__ Bt,
    short* __restrict__ outb, const float* __restrict__ bias)
{
    const int K = INNER, Nout = INNER;
    __shared__ short As[128 * GBK];
    __shared__ short Bs[64 * GBK];
    const int t = threadIdx.x;
    const int w = t >> 6, lane = t & 63;
    const int quad = lane >> 4, l16 = lane & 15;
    const int m0 = blockIdx.y * 128, n0 = blockIdx.x * 64;
    const int wm = (w >> 1) * 64, wn = (w & 1) * 32;

    f32x4 acc[4][2];
    #pragma unroll
    for (int i = 0; i < 4; ++i)
        #pragma unroll
        for (int j = 0; j < 2; ++j) acc[i][j] = (f32x4){0.f, 0.f, 0.f, 0.f};

    for (int kt = 0; kt < K; kt += GBK) {
        __syncthreads();
        #pragma unroll
        for (int i = 0; i < 2; ++i) {
            const int j = w * 2 + i;
            const int c = j * 64 + lane;
            gld16(&A[(size_t)(m0 + (c >> 2)) * K + kt + (c & 3) * 8],
                  (char*)As + j * 1024);
        }
        {
            const int c = w * 64 + lane;
            gld16(&Bt[(size_t)(n0 + (c >> 2)) * K + kt + (c & 3) * 8],
                  (char*)Bs + w * 1024);
        }
        __syncthreads();

        bf16x8 af[4], bfr[2];
        #pragma unroll
        for (int mt = 0; mt < 4; ++mt)
            af[mt] = *(bf16x8*)&As[(wm + mt * 16 + l16) * GBK + quad * 8];
        #pragma unroll
        for (int nt = 0; nt < 2; ++nt)
            bfr[nt] = *(bf16x8*)&Bs[(wn + nt * 16 + l16) * GBK + quad * 8];
        #pragma unroll
        for (int mt = 0; mt < 4; ++mt)
            #pragma unroll
            for (int nt = 0; nt < 2; ++nt)
                acc[mt][nt] = __builtin_amdgcn_mfma_f32_16x16x32_bf16(
                    af[mt], bfr[nt], acc[mt][nt], 0, 0, 0);
    }

    #pragma unroll
    for (int mt = 0; mt < 4; ++mt)
        #pragma unroll
        for (int r = 0; r < 4; ++r) {
            const int m = m0 + wm + mt * 16 + quad * 4 + r;
            #pragma unroll
            for (int nt = 0; nt < 2; ++nt) {
                const int n = n0 + wn + nt * 16 + l16;
                outb[(size_t)m * Nout + n] = fbf(acc[mt][nt][r] + bias[n]);
            }
        }
}

// ---------------------------------------------------------------------------
// bf16-MFMA flash attention v6: S^T form, no-max softmax, j-split,
// register-direct P *with K=32 PV via permuted V^T columns*:
// stored col p = q*8 + jt*4 + r holds j' = jt*16 + q*4 + r, so the packed
// exp2 results [jt=2cc regs | jt=2cc+1 regs] ARE the 16x16x32 A-operand and
// the B-frag is one contiguous ds_read_b128. PV: 16 K=32 MFMAs/wave-iter
// (vs 32 K=16 in v5); l-sum: 4 MFMAs with constant ones8 B-frag.
// K/V double-buffered, one barrier/iter. Block = 512 thr = 8 waves:
// waves 0-3 j in [0,1024), 4-7 j in [1024,2048), same 128 Q rows;
// O,l additive -> one-time LDS combine. q PRE-SCALED by 0.125*log2(e).
// ---------------------------------------------------------------------------
#define QT 128
#define JT 64
#define KSTR 72      // 144 B rows: 16B-aligned for b128, 2-way bank alias max
#define MH (MM / 2)  // 1024 j's per wave-group
#define NIT (MH / JT)

__global__ __launch_bounds__(512) void attention_mfma(
    const short* __restrict__ q, const short* __restrict__ kv,
    short* __restrict__ o)
{
    const int b = blockIdx.z, h = blockIdx.y;
    const int i0 = blockIdx.x * QT;
    const int t = threadIdx.x;
    const int wave = t >> 6, lane = t & 63;
    const int w4 = wave & 3, hh = wave >> 2;   // row-group, j-half
    const int quad = lane >> 4, l16 = lane & 15;

    // LDS: double-buffered K/V tiles; combine buffers overlay afterwards.
    __shared__ __align__(16) char smem[73728];
    typedef short KT[2][64][KSTR];                       // [half][row][col]
    KT* Ks = (KT*)smem;                                  // Ks[buf]: 18432 B each
    KT* Vt = (KT*)(smem + 36864);                        // Vt[buf] (permuted cols)
    float (*Obuf)[32][68] = (float(*)[32][68])(smem);    // 34816 B (overlay)
    float (*Lbuf)[32]     = (float(*)[32])(smem + 34816);

    // Q fragments (B operand of QK): col i = l16, k = cc*32 + quad*8
    bf16x8 qf[2][2];
    #pragma unroll
    for (int it = 0; it < 2; ++it) {
        const int row = i0 + w4 * 32 + it * 16 + l16;
        const short* qp = &q[((size_t)(b * NN + row)) * INNER + h * DH];
        qf[it][0] = *(const bf16x8*)&qp[quad * 8];
        qf[it][1] = *(const bf16x8*)&qp[32 + quad * 8];
    }

    f32x4 Oa[2][4];   // [it][dt]: O rows quad*4+r, col dt*16+l16 (unnormalized)
    f32x4 La[2];      // [it]: l rows quad*4+r (identical across l16 lanes)
    #pragma unroll
    for (int it = 0; it < 2; ++it) {
        La[it] = (f32x4){0.f, 0.f, 0.f, 0.f};
        #pragma unroll
        for (int dt = 0; dt < 4; ++dt) Oa[it][dt] = (f32x4){0.f, 0.f, 0.f, 0.f};
    }

    const bf16x8 ones8 = {(short)0x3F80, (short)0x3F80, (short)0x3F80, (short)0x3F80,
                          (short)0x3F80, (short)0x3F80, (short)0x3F80, (short)0x3F80};

    // staging: threads 0-255 stage j-half 0, 256-511 half 1
    const int tt = t & 255, th = t >> 8;
    const int kjj = tt >> 3, kdq = (tt & 7) * 8;   // K: 32 rows x 8 chunks, x2
    const int vjp = tt & 31, vd0 = (tt >> 5) * 8;  // V: j-pair, 8 d each

    // permuted V^T column for this thread's j-pair (pair stays adjacent):
    //   j-local = 2*vjp in [0,64): group g=j>>5; within group j'=j&31:
    //   jt=(j'>>4), qd=(j'>>2)&3, r=j'&3 -> p = qd*8 + jt*4 + r
    const int jl0 = 2 * vjp;
    const int vcol = (jl0 >> 5) * 32 + (((jl0 >> 2) & 3) * 8)
                   + (((jl0 >> 4) & 1) * 4) + (jl0 & 3);

    auto stage = [&](int pb, int jj0n) {
        const int j0g = th * MH + jj0n;
        #pragma unroll
        for (int ii = 0; ii < 2; ++ii) {
            const int jj = ii * 32 + kjj;
            *(bf16x8*)&Ks[pb][th][jj][kdq] =
                *(const bf16x8*)&kv[((size_t)(b * MM + j0g + jj)) * KVS + h * DH + kdq];
        }
        const int jg = j0g + jl0;
        bf16x8 va = *(const bf16x8*)&kv[((size_t)(b * MM + jg))     * KVS + 512 + h * DH + vd0];
        bf16x8 vb = *(const bf16x8*)&kv[((size_t)(b * MM + jg + 1)) * KVS + 512 + h * DH + vd0];
        #pragma unroll
        for (int i = 0; i < 8; ++i) {
            short2 pr; pr.x = va[i]; pr.y = vb[i];
            *(short2*)&Vt[pb][th][vd0 + i][vcol] = pr;
        }
    };

    stage(0, 0);
    __syncthreads();

    for (int itr = 0; itr < NIT; ++itr) {
        const int p = itr & 1;
        if (itr + 1 < NIT) stage(p ^ 1, (itr + 1) * JT);

        #pragma unroll
        for (int cc = 0; cc < 2; ++cc) {
            // S^T = K Q^T for jt = 2cc, 2cc+1 (K-frags shared by both i-tiles)
            f32x4 Sc[2][2];   // [jtl][it]
            #pragma unroll
            for (int jtl = 0; jtl < 2; ++jtl) {
                const int jt = cc * 2 + jtl;
                bf16x8 kb0 = *(bf16x8*)&Ks[p][hh][jt * 16 + l16][quad * 8];
                bf16x8 kb1 = *(bf16x8*)&Ks[p][hh][jt * 16 + l16][32 + quad * 8];
                #pragma unroll
                for (int it = 0; it < 2; ++it) {
                    f32x4 c = (f32x4){0.f, 0.f, 0.f, 0.f};
                    c = __builtin_amdgcn_mfma_f32_16x16x32_bf16(kb0, qf[it][0], c, 0, 0, 0);
                    c = __builtin_amdgcn_mfma_f32_16x16x32_bf16(kb1, qf[it][1], c, 0, 0, 0);
                    Sc[jtl][it] = c;
                }
            }

            // p = exp2(s); pack 8 values -> 16x16x32 A-frag (matches permuted V^T)
            bf16x8 p8[2];
            #pragma unroll
            for (int it = 0; it < 2; ++it) {
                const float e0 = exp2f(Sc[0][it][0]), e1 = exp2f(Sc[0][it][1]);
                const float e2 = exp2f(Sc[0][it][2]), e3 = exp2f(Sc[0][it][3]);
                const float f0 = exp2f(Sc[1][it][0]), f1 = exp2f(Sc[1][it][1]);
                const float f2 = exp2f(Sc[1][it][2]), f3 = exp2f(Sc[1][it][3]);
                uint4 pk;   // low short first (truncation-pack)
                pk.x = __builtin_amdgcn_perm(__builtin_bit_cast(unsigned, e1),
                                             __builtin_bit_cast(unsigned, e0), 0x07060302u);
                pk.y = __builtin_amdgcn_perm(__builtin_bit_cast(unsigned, e3),
                                             __builtin_bit_cast(unsigned, e2), 0x07060302u);
                pk.z = __builtin_amdgcn_perm(__builtin_bit_cast(unsigned, f1),
                                             __builtin_bit_cast(unsigned, f0), 0x07060302u);
                pk.w = __builtin_amdgcn_perm(__builtin_bit_cast(unsigned, f3),
                                             __builtin_bit_cast(unsigned, f2), 0x07060302u);
                p8[it] = __builtin_bit_cast(bf16x8, pk);
            }

            // O += P V  (B-frag: one b128 from permuted V^T)
            #pragma unroll
            for (int dt = 0; dt < 4; ++dt) {
                bf16x8 vb8 = *(bf16x8*)&Vt[p][hh][dt * 16 + l16][cc * 32 + quad * 8];
                Oa[0][dt] = __builtin_amdgcn_mfma_f32_16x16x32_bf16(p8[0], vb8, Oa[0][dt], 0, 0, 0);
                Oa[1][dt] = __builtin_amdgcn_mfma_f32_16x16x32_bf16(p8[1], vb8, Oa[1][dt], 0, 0, 0);
            }
            // l += P . 1 (constant ones B-frag; permutation-invariant)
            La[0] = __builtin_amdgcn_mfma_f32_16x16x32_bf16(p8[0], ones8, La[0], 0, 0, 0);
            La[1] = __builtin_amdgcn_mfma_f32_16x16x32_bf16(p8[1], ones8, La[1], 0, 0, 0);
        }
        __syncthreads();
    }

    // ---- combine the two j-halves (O, l additive) via LDS ----
    if (wave >= 4) {
        #pragma unroll
        for (int it = 0; it < 2; ++it) {
            #pragma unroll
            for (int r = 0; r < 4; ++r) {
                const int qr = it * 16 + quad * 4 + r;
                #pragma unroll
                for (int dt = 0; dt < 4; ++dt)
                    Obuf[w4][qr][dt * 16 + l16] = Oa[it][dt][r];
                if (l16 == 0) Lbuf[w4][qr] = La[it][r];
            }
        }
    }
    __syncthreads();
    if (wave < 4) {
        #pragma unroll
        for (int it = 0; it < 2; ++it) {
            #pragma unroll
            for (int r = 0; r < 4; ++r) {
                const int qr = it * 16 + quad * 4 + r;
                const float ltot = La[it][r] + Lbuf[w4][qr];  // all l16 lanes identical
                const float inv = 1.f / ltot;
                const int row = i0 + w4 * 32 + qr;
                #pragma unroll
                for (int dt = 0; dt < 4; ++dt) {
                    const float val = Oa[it][dt][r] + Obuf[w4][qr][dt * 16 + l16];
                    o[((size_t)(b * NN + row)) * INNER + h * DH + dt * 16 + l16] =
                        fbf(val * inv);
                }
            }
        }
    }
}

// ---------------------------------------------------------------------------
// Launch
// ---------------------------------------------------------------------------
extern "C" void kernel_launch(void* const* d_in, const int* in_sizes, int n_in,
                              void* d_out, int out_size, void* d_ws, size_t ws_size,
                              hipStream_t stream)
{
    const float* x     = (const float*)d_in[0];
    const float* cond  = (const float*)d_in[1];
    const float* lnx_g = (const float*)d_in[2];
    const float* lnx_b = (const float*)d_in[3];
    const float* lnc_g = (const float*)d_in[4];
    const float* lnc_b = (const float*)d_in[5];
    const float* Wq    = (const float*)d_in[6];
    const float* Wk    = (const float*)d_in[7];
    const float* Wv    = (const float*)d_in[8];
    const float* Wo    = (const float*)d_in[9];
    const float* bo    = (const float*)d_in[10];
    const float* lnf_g = (const float*)d_in[11];
    const float* lnf_b = (const float*)d_in[12];
    float* out = (float*)d_out;
    char* ws = (char*)d_ws;

    const int R = BB * NN;  // 8192

    // workspace layout (bytes, 16B-aligned)
    short* xn_bf  = (short*)(ws);                    //  8 MB
    short* cn_bf  = (short*)(ws + (8u << 20));       // 12 MB
    short* Wq_t   = (short*)(ws + (20u << 20));      // 0.5 MB
    short* Wo_t   = (short*)(ws + (21u << 20));      // 0.5 MB
    short* Wkv_t  = (short*)(ws + (22u << 20));      // 1.5 MB
    short* qb     = (short*)(ws + (24u << 20));      //  8 MB
    short* kvb    = (short*)(ws + (32u << 20));      // 16 MB
    short* ab     = (short*)(ws + (48u << 20));      //  8 MB
    short* ob     = (short*)(ws + (56u << 20));      //  8 MB

    transpose4<<<dim3(16, 80), 256, 0, stream>>>(Wq, Wk, Wv, Wo, Wq_t, Wkv_t, Wo_t);

    ln2_bf16<<<dim3(R, 2), 256, 0, stream>>>(
        x, cond, lnx_g, lnx_b, lnc_g, lnc_b, xn_bf, cn_bf);

    // q = (xn @ Wq)*0.125*log2e ; [k|v] = cn @ [Wk|Wv]
    qkv_gemm<<<dim3(12, R / 128), 256, 0, stream>>>(
        xn_bf, cn_bf, Wq_t, Wkv_t, qb, kvb, 0.125f * 1.44269504089f);

    attention_mfma<<<dim3(NN / QT, NH, BB), 512, 0, stream>>>(qb, kvb, ab);

    // o-proj: bf16 out + bias (residual folded into the final LN)
    oproj_gemm<<<dim3(INNER / 64, R / 128), 256, 0, stream>>>(ab, Wo_t, ob, bo);

    layernorm_res_f32<<<R, 256, 0, stream>>>(ob, x, lnf_g, lnf_b, out);
}

// Round 9
// 228.405 us; speedup vs baseline: 1.0551x; 1.0409x over previous
//
#include <hip/hip_runtime.h>
#include <hip/hip_bf16.h>
#include <math.h>

// Problem constants (CrossAttention_14955076125227)
//   B=4, N=2048, M=2048, Dq=512, Dc=768, H=8, Dh=64, inner=512
#define BB 4
#define NN 2048
#define MM 2048
#define DQ 512
#define DC 768
#define NH 8
#define DH 64
#define INNER 512
#define KVS 1024   // fused K|V row stride (bf16 elems)

typedef short bf16x8 __attribute__((ext_vector_type(8)));
typedef float f32x4  __attribute__((ext_vector_type(4)));

__device__ inline short fbf(float f) {
    __hip_bfloat16 h = __float2bfloat16(f);
    return __builtin_bit_cast(short, h);
}

// async global->LDS, 16 B per lane. LDS dest is wave-uniform base; HW adds lane*16.
__device__ inline void gld16(const void* gptr, void* lds_uniform_base) {
    __builtin_amdgcn_global_load_lds(
        (const __attribute__((address_space(1))) void*)gptr,
        (__attribute__((address_space(3))) void*)lds_uniform_base, 16, 0, 0);
}

// ---------------------------------------------------------------------------
// Fused prep kernel: LN(x), LN(cond) -> bf16, and all 4 weight transposes.
// grid: 17664 blocks x 256 thr.
//   bx < 8192        : LN row bx of x     (D=512)
//   bx < 16384       : LN row bx-8192 of cond (D=768)
//   else             : transpose tile tb = bx-16384 (16 n-tiles x 80 k-tiles)
// ---------------------------------------------------------------------------
__global__ __launch_bounds__(256) void prep_k(
    const float* __restrict__ x, const float* __restrict__ cond,
    const float* __restrict__ gx, const float* __restrict__ bx_,
    const float* __restrict__ gc, const float* __restrict__ bc,
    short* __restrict__ xn, short* __restrict__ cn,
    const float* __restrict__ Wq, const float* __restrict__ Wk,
    const float* __restrict__ Wv, const float* __restrict__ Wo,
    short* __restrict__ Wqt, short* __restrict__ Wkvt, short* __restrict__ Wot)
{
    const int bxid = blockIdx.x;
    const int t = threadIdx.x;

    if (bxid < 16384) {   // ---- LayerNorm path ----
        const int which = bxid >> 13;            // 0: x, 1: cond
        const int row   = bxid & 8191;
        const float* in = which ? cond : x;
        const float* g  = which ? gc : gx;
        const float* bb = which ? bc : bx_;
        short* out      = which ? cn : xn;
        const int D     = which ? DC : DQ;

        const float* xr = in + (size_t)row * D;
        float s = 0.f, s2 = 0.f;
        for (int d = t; d < D; d += 256) {
            float v = xr[d];
            s += v; s2 += v * v;
        }
        __shared__ float red[2][4];
        #pragma unroll
        for (int off = 32; off; off >>= 1) {
            s  += __shfl_down(s,  off, 64);
            s2 += __shfl_down(s2, off, 64);
        }
        const int wave = t >> 6, lane = t & 63;
        if (lane == 0) { red[0][wave] = s; red[1][wave] = s2; }
        __syncthreads();
        if (t == 0) {
            float ts = red[0][0] + red[0][1] + red[0][2] + red[0][3];
            float t2 = red[1][0] + red[1][1] + red[1][2] + red[1][3];
            float mu = ts / (float)D;
            float var = t2 / (float)D - mu * mu;
            red[0][0] = mu;
            red[1][0] = rsqrtf(var + 1e-5f);
        }
        __syncthreads();
        const float mu = red[0][0], rstd = red[1][0];
        short* o = out + (size_t)row * D;
        for (int d = t; d < D; d += 256)
            o[d] = fbf((xr[d] - mu) * rstd * g[d] + bb[d]);
    } else {              // ---- weight transpose path ----
        const int tb = bxid - 16384;
        const int y = tb >> 4;
        const int n0 = (tb & 15) * 32;
        const float* W; short* Wt; int K, k0;
        if (y < 16)      { W = Wq; Wt = Wqt;  K = DQ; k0 = y * 32; }
        else if (y < 40) { W = Wk; Wt = Wkvt; K = DC; k0 = (y - 16) * 32; }
        else if (y < 64) { W = Wv; Wt = Wkvt + (size_t)512 * DC; K = DC; k0 = (y - 40) * 32; }
        else             { W = Wo; Wt = Wot;  K = DQ; k0 = (y - 64) * 32; }

        __shared__ float tile[32][33];
        const int r = t >> 3, c4 = (t & 7) * 4;
        float4 vv = *(const float4*)&W[(size_t)(k0 + r) * 512 + n0 + c4];
        tile[c4 + 0][r] = vv.x; tile[c4 + 1][r] = vv.y;
        tile[c4 + 2][r] = vv.z; tile[c4 + 3][r] = vv.w;
        __syncthreads();
        short4 sv;
        sv.x = fbf(tile[r][c4 + 0]); sv.y = fbf(tile[r][c4 + 1]);
        sv.z = fbf(tile[r][c4 + 2]); sv.w = fbf(tile[r][c4 + 3]);
        *(short4*)&Wt[(size_t)(n0 + r) * K + k0 + c4] = sv;
    }
}

// ---------------------------------------------------------------------------
// Final LayerNorm with fused residual: out = LN(bf16(ob) + x), D=512.
// ---------------------------------------------------------------------------
__global__ __launch_bounds__(256) void layernorm_res_f32(
    const short* __restrict__ ob, const float* __restrict__ x,
    const float* __restrict__ g, const float* __restrict__ b,
    float* __restrict__ out)
{
    const int row = blockIdx.x;
    const int t = threadIdx.x;
    const size_t base = (size_t)row * DQ;
    float v0, v1;
    {
        unsigned u0 = (unsigned)(unsigned short)ob[base + t];
        unsigned u1 = (unsigned)(unsigned short)ob[base + t + 256];
        v0 = __builtin_bit_cast(float, u0 << 16) + x[base + t];
        v1 = __builtin_bit_cast(float, u1 << 16) + x[base + t + 256];
    }
    float s = v0 + v1, s2 = v0 * v0 + v1 * v1;
    __shared__ float red[2][4];
    #pragma unroll
    for (int off = 32; off; off >>= 1) {
        s  += __shfl_down(s,  off, 64);
        s2 += __shfl_down(s2, off, 64);
    }
    const int wave = t >> 6, lane = t & 63;
    if (lane == 0) { red[0][wave] = s; red[1][wave] = s2; }
    __syncthreads();
    if (t == 0) {
        float ts = red[0][0] + red[0][1] + red[0][2] + red[0][3];
        float t2 = red[1][0] + red[1][1] + red[1][2] + red[1][3];
        float mu = ts / (float)DQ;
        float var = t2 / (float)DQ - mu * mu;
        red[0][0] = mu;
        red[1][0] = rsqrtf(var + 1e-5f);
    }
    __syncthreads();
    const float mu = red[0][0], rstd = red[1][0];
    out[base + t]       = (v0 - mu) * rstd * g[t]       + b[t];
    out[base + t + 256] = (v1 - mu) * rstd * g[t + 256] + b[t + 256];
}

// ---------------------------------------------------------------------------
// Fused q+kv projection GEMM. grid (12, 64):
//  x<4 : q = (xn @ Wq)*qsc, Nout=512, K=512
//  x>=4: kv = cn @ [Wk|Wv], Nout=1024, K=768
// ---------------------------------------------------------------------------
#define GBK 32

__global__ __launch_bounds__(256) void qkv_gemm(
    const short* __restrict__ xn, const short* __restrict__ cn,
    const short* __restrict__ Wqt, const short* __restrict__ Wkvt,
    short* __restrict__ qb, short* __restrict__ kvb, float qsc)
{
    const short* A; const short* Bt; short* outp; int K, Nout, n0; float sc;
    if (blockIdx.x < 4) {
        A = xn; Bt = Wqt; outp = qb; K = DQ; Nout = 512;
        n0 = blockIdx.x * 128; sc = qsc;
    } else {
        A = cn; Bt = Wkvt; outp = kvb; K = DC; Nout = 1024;
        n0 = (blockIdx.x - 4) * 128; sc = 1.f;
    }
    __shared__ short As[128 * GBK];
    __shared__ short Bs[128 * GBK];
    const int t = threadIdx.x;
    const int w = t >> 6, lane = t & 63;
    const int quad = lane >> 4, l16 = lane & 15;
    const int m0 = blockIdx.y * 128;
    const int wm = (w >> 1) * 64, wn = (w & 1) * 64;

    f32x4 acc[4][4];
    #pragma unroll
    for (int i = 0; i < 4; ++i)
        #pragma unroll
        for (int j = 0; j < 4; ++j) acc[i][j] = (f32x4){0.f, 0.f, 0.f, 0.f};

    for (int kt = 0; kt < K; kt += GBK) {
        __syncthreads();
        #pragma unroll
        for (int i = 0; i < 2; ++i) {
            const int j = w * 2 + i;
            const int c = j * 64 + lane;
            gld16(&A[(size_t)(m0 + (c >> 2)) * K + kt + (c & 3) * 8],
                  (char*)As + j * 1024);
            gld16(&Bt[(size_t)(n0 + (c >> 2)) * K + kt + (c & 3) * 8],
                  (char*)Bs + j * 1024);
        }
        __syncthreads();

        bf16x8 af[4], bfr[4];
        #pragma unroll
        for (int mt = 0; mt < 4; ++mt)
            af[mt] = *(bf16x8*)&As[(wm + mt * 16 + l16) * GBK + quad * 8];
        #pragma unroll
        for (int nt = 0; nt < 4; ++nt)
            bfr[nt] = *(bf16x8*)&Bs[(wn + nt * 16 + l16) * GBK + quad * 8];
        #pragma unroll
        for (int mt = 0; mt < 4; ++mt)
            #pragma unroll
            for (int nt = 0; nt < 4; ++nt)
                acc[mt][nt] = __builtin_amdgcn_mfma_f32_16x16x32_bf16(
                    af[mt], bfr[nt], acc[mt][nt], 0, 0, 0);
    }

    #pragma unroll
    for (int mt = 0; mt < 4; ++mt)
        #pragma unroll
        for (int r = 0; r < 4; ++r) {
            const int m = m0 + wm + mt * 16 + quad * 4 + r;
            #pragma unroll
            for (int nt = 0; nt < 4; ++nt) {
                const int n = n0 + wn + nt * 16 + l16;
                outp[(size_t)m * Nout + n] = fbf(acc[mt][nt][r] * sc);
            }
        }
}

// ---------------------------------------------------------------------------
// o-proj GEMM: C = ab @ Wot^T + bias, bf16 out. Tile 128x64.
// ---------------------------------------------------------------------------
__global__ __launch_bounds__(256) void oproj_gemm(
    const short* __restrict__ A, const short* __restrict__ Bt,
    short* __restrict__ outb, const float* __restrict__ bias)
{
    const int K = INNER, Nout = INNER;
    __shared__ short As[128 * GBK];
    __shared__ short Bs[64 * GBK];
    const int t = threadIdx.x;
    const int w = t >> 6, lane = t & 63;
    const int quad = lane >> 4, l16 = lane & 15;
    const int m0 = blockIdx.y * 128, n0 = blockIdx.x * 64;
    const int wm = (w >> 1) * 64, wn = (w & 1) * 32;

    f32x4 acc[4][2];
    #pragma unroll
    for (int i = 0; i < 4; ++i)
        #pragma unroll
        for (int j = 0; j < 2; ++j) acc[i][j] = (f32x4){0.f, 0.f, 0.f, 0.f};

    for (int kt = 0; kt < K; kt += GBK) {
        __syncthreads();
        #pragma unroll
        for (int i = 0; i < 2; ++i) {
            const int j = w * 2 + i;
            const int c = j * 64 + lane;
            gld16(&A[(size_t)(m0 + (c >> 2)) * K + kt + (c & 3) * 8],
                  (char*)As + j * 1024);
        }
        {
            const int c = w * 64 + lane;
            gld16(&Bt[(size_t)(n0 + (c >> 2)) * K + kt + (c & 3) * 8],
                  (char*)Bs + w * 1024);
        }
        __syncthreads();

        bf16x8 af[4], bfr[2];
        #pragma unroll
        for (int mt = 0; mt < 4; ++mt)
            af[mt] = *(bf16x8*)&As[(wm + mt * 16 + l16) * GBK + quad * 8];
        #pragma unroll
        for (int nt = 0; nt < 2; ++nt)
            bfr[nt] = *(bf16x8*)&Bs[(wn + nt * 16 + l16) * GBK + quad * 8];
        #pragma unroll
        for (int mt = 0; mt < 4; ++mt)
            #pragma unroll
            for (int nt = 0; nt < 2; ++nt)
                acc[mt][nt] = __builtin_amdgcn_mfma_f32_16x16x32_bf16(
                    af[mt], bfr[nt], acc[mt][nt], 0, 0, 0);
    }

    #pragma unroll
    for (int mt = 0; mt < 4; ++mt)
        #pragma unroll
        for (int r = 0; r < 4; ++r) {
            const int m = m0 + wm + mt * 16 + quad * 4 + r;
            #pragma unroll
            for (int nt = 0; nt < 2; ++nt) {
                const int n = n0 + wn + nt * 16 + l16;
                outb[(size_t)m * Nout + n] = fbf(acc[mt][nt][r] + bias[n]);
            }
        }
}

// ---------------------------------------------------------------------------
// bf16-MFMA flash attention v7: v6 dataflow (S^T, no-max softmax, j-split,
// register-direct K=32 PV via permuted V^T) + SOFTWARE-PIPELINED STAGING:
// global loads for iter+1 issue BEFORE compute of iter; the dependent
// ds_writes happen AFTER compute. The vmcnt wait thus lands behind ~500 cyc
// of MFMA/exp work instead of stalling all waves right after the barrier.
// Per-iter address math replaced by pointer increments.
// ---------------------------------------------------------------------------
#define QT 128
#define JT 64
#define KSTR 72      // 144 B rows: 16B-aligned for b128, 2-way bank alias max
#define MH (MM / 2)  // 1024 j's per wave-group
#define NIT (MH / JT)

__global__ __launch_bounds__(512) void attention_mfma(
    const short* __restrict__ q, const short* __restrict__ kv,
    short* __restrict__ o)
{
    const int b = blockIdx.z, h = blockIdx.y;
    const int i0 = blockIdx.x * QT;
    const int t = threadIdx.x;
    const int wave = t >> 6, lane = t & 63;
    const int w4 = wave & 3, hh = wave >> 2;   // row-group, j-half
    const int quad = lane >> 4, l16 = lane & 15;

    // LDS: double-buffered K/V tiles; combine buffers overlay afterwards.
    __shared__ __align__(16) char smem[73728];
    typedef short KT[2][64][KSTR];                       // [half][row][col]
    KT* Ks = (KT*)smem;                                  // Ks[buf]: 18432 B each
    KT* Vt = (KT*)(smem + 36864);                        // Vt[buf] (permuted cols)
    float (*Obuf)[32][68] = (float(*)[32][68])(smem);    // 34816 B (overlay)
    float (*Lbuf)[32]     = (float(*)[32])(smem + 34816);

    // Q fragments (B operand of QK): col i = l16, k = cc*32 + quad*8
    bf16x8 qf[2][2];
    #pragma unroll
    for (int it = 0; it < 2; ++it) {
        const int row = i0 + w4 * 32 + it * 16 + l16;
        const short* qp = &q[((size_t)(b * NN + row)) * INNER + h * DH];
        qf[it][0] = *(const bf16x8*)&qp[quad * 8];
        qf[it][1] = *(const bf16x8*)&qp[32 + quad * 8];
    }

    f32x4 Oa[2][4];   // [it][dt]: O rows quad*4+r, col dt*16+l16 (unnormalized)
    f32x4 La[2];      // [it]: l rows quad*4+r (identical across l16 lanes)
    #pragma unroll
    for (int it = 0; it < 2; ++it) {
        La[it] = (f32x4){0.f, 0.f, 0.f, 0.f};
        #pragma unroll
        for (int dt = 0; dt < 4; ++dt) Oa[it][dt] = (f32x4){0.f, 0.f, 0.f, 0.f};
    }

    const bf16x8 ones8 = {(short)0x3F80, (short)0x3F80, (short)0x3F80, (short)0x3F80,
                          (short)0x3F80, (short)0x3F80, (short)0x3F80, (short)0x3F80};

    // staging assignments: threads 0-255 stage j-half 0, 256-511 half 1
    const int tt = t & 255, th = t >> 8;
    const int kjj = tt >> 3, kdq = (tt & 7) * 8;   // K: 32 rows x 8 chunks, x2
    const int vjp = tt & 31, vd0 = (tt >> 5) * 8;  // V: j-pair, 8 d each

    // permuted V^T column for this thread's j-pair:
    //   j' = jt*16 + qd*4 + r  stored at  p = qd*8 + jt*4 + r
    const int jl0 = 2 * vjp;
    const int vcol = (jl0 >> 5) * 32 + (((jl0 >> 2) & 3) * 8)
                   + (((jl0 >> 4) & 1) * 4) + (jl0 & 3);

    // hoisted global pointers (advance by JT*KVS per iteration)
    const short* kp0 = kv + ((size_t)(b * MM + th * MH + kjj))      * KVS + h * DH + kdq;
    const short* kp1 = kv + ((size_t)(b * MM + th * MH + kjj + 32)) * KVS + h * DH + kdq;
    const short* vp0 = kv + ((size_t)(b * MM + th * MH + jl0))      * KVS + 512 + h * DH + vd0;
    const short* vp1 = vp0 + KVS;

    bf16x8 ka, kb2, va, vb;   // staging registers (prefetch)
    auto load = [&]() {
        ka  = *(const bf16x8*)kp0;
        kb2 = *(const bf16x8*)kp1;
        va  = *(const bf16x8*)vp0;
        vb  = *(const bf16x8*)vp1;
        kp0 += (size_t)JT * KVS; kp1 += (size_t)JT * KVS;
        vp0 += (size_t)JT * KVS; vp1 += (size_t)JT * KVS;
    };
    auto store = [&](int pb) {
        *(bf16x8*)&Ks[pb][th][kjj][kdq]      = ka;
        *(bf16x8*)&Ks[pb][th][kjj + 32][kdq] = kb2;
        #pragma unroll
        for (int i = 0; i < 8; ++i) {
            short2 pr; pr.x = va[i]; pr.y = vb[i];
            *(short2*)&Vt[pb][th][vd0 + i][vcol] = pr;
        }
    };

    load(); store(0);
    __syncthreads();

    for (int itr = 0; itr < NIT; ++itr) {
        const int p = itr & 1;
        const bool more = (itr + 1 < NIT);
        if (more) load();   // global loads in flight during compute

        #pragma unroll
        for (int cc = 0; cc < 2; ++cc) {
            // S^T = K Q^T for jt = 2cc, 2cc+1 (K-frags shared by both i-tiles)
            f32x4 Sc[2][2];   // [jtl][it]
            #pragma unroll
            for (int jtl = 0; jtl < 2; ++jtl) {
                const int jt = cc * 2 + jtl;
                bf16x8 kf0 = *(bf16x8*)&Ks[p][hh][jt * 16 + l16][quad * 8];
                bf16x8 kf1 = *(bf16x8*)&Ks[p][hh][jt * 16 + l16][32 + quad * 8];
                #pragma unroll
                for (int it = 0; it < 2; ++it) {
                    f32x4 c = (f32x4){0.f, 0.f, 0.f, 0.f};
                    c = __builtin_amdgcn_mfma_f32_16x16x32_bf16(kf0, qf[it][0], c, 0, 0, 0);
                    c = __builtin_amdgcn_mfma_f32_16x16x32_bf16(kf1, qf[it][1], c, 0, 0, 0);
                    Sc[jtl][it] = c;
                }
            }

            // p = exp2(s); pack 8 values -> 16x16x32 A-frag (matches permuted V^T)
            bf16x8 p8[2];
            #pragma unroll
            for (int it = 0; it < 2; ++it) {
                const float e0 = exp2f(Sc[0][it][0]), e1 = exp2f(Sc[0][it][1]);
                const float e2 = exp2f(Sc[0][it][2]), e3 = exp2f(Sc[0][it][3]);
                const float f0 = exp2f(Sc[1][it][0]), f1 = exp2f(Sc[1][it][1]);
                const float f2 = exp2f(Sc[1][it][2]), f3 = exp2f(Sc[1][it][3]);
                uint4 pk;   // low short first (truncation-pack)
                pk.x = __builtin_amdgcn_perm(__builtin_bit_cast(unsigned, e1),
                                             __builtin_bit_cast(unsigned, e0), 0x07060302u);
                pk.y = __builtin_amdgcn_perm(__builtin_bit_cast(unsigned, e3),
                                             __builtin_bit_cast(unsigned, e2), 0x07060302u);
                pk.z = __builtin_amdgcn_perm(__builtin_bit_cast(unsigned, f1),
                                             __builtin_bit_cast(unsigned, f0), 0x07060302u);
                pk.w = __builtin_amdgcn_perm(__builtin_bit_cast(unsigned, f3),
                                             __builtin_bit_cast(unsigned, f2), 0x07060302u);
                p8[it] = __builtin_bit_cast(bf16x8, pk);
            }

            // O += P V  (B-frag: one b128 from permuted V^T)
            #pragma unroll
            for (int dt = 0; dt < 4; ++dt) {
                bf16x8 vb8 = *(bf16x8*)&Vt[p][hh][dt * 16 + l16][cc * 32 + quad * 8];
                Oa[0][dt] = __builtin_amdgcn_mfma_f32_16x16x32_bf16(p8[0], vb8, Oa[0][dt], 0, 0, 0);
                Oa[1][dt] = __builtin_amdgcn_mfma_f32_16x16x32_bf16(p8[1], vb8, Oa[1][dt], 0, 0, 0);
            }
            // l += P . 1 (constant ones B-frag; permutation-invariant)
            La[0] = __builtin_amdgcn_mfma_f32_16x16x32_bf16(p8[0], ones8, La[0], 0, 0, 0);
            La[1] = __builtin_amdgcn_mfma_f32_16x16x32_bf16(p8[1], ones8, La[1], 0, 0, 0);
        }

        if (more) store(p ^ 1);   // vmcnt wait lands here, after compute
        __syncthreads();
    }

    // ---- combine the two j-halves (O, l additive) via LDS ----
    if (wave >= 4) {
        #pragma unroll
        for (int it = 0; it < 2; ++it) {
            #pragma unroll
            for (int r = 0; r < 4; ++r) {
                const int qr = it * 16 + quad * 4 + r;
                #pragma unroll
                for (int dt = 0; dt < 4; ++dt)
                    Obuf[w4][qr][dt * 16 + l16] = Oa[it][dt][r];
                if (l16 == 0) Lbuf[w4][qr] = La[it][r];
            }
        }
    }
    __syncthreads();
    if (wave < 4) {
        #pragma unroll
        for (int it = 0; it < 2; ++it) {
            #pragma unroll
            for (int r = 0; r < 4; ++r) {
                const int qr = it * 16 + quad * 4 + r;
                const float ltot = La[it][r] + Lbuf[w4][qr];  // all l16 lanes identical
                const float inv = 1.f / ltot;
                const int row = i0 + w4 * 32 + qr;
                #pragma unroll
                for (int dt = 0; dt < 4; ++dt) {
                    const float val = Oa[it][dt][r] + Obuf[w4][qr][dt * 16 + l16];
                    o[((size_t)(b * NN + row)) * INNER + h * DH + dt * 16 + l16] =
                        fbf(val * inv);
                }
            }
        }
    }
}

// ---------------------------------------------------------------------------
// Launch
// ---------------------------------------------------------------------------
extern "C" void kernel_launch(void* const* d_in, const int* in_sizes, int n_in,
                              void* d_out, int out_size, void* d_ws, size_t ws_size,
                              hipStream_t stream)
{
    const float* x     = (const float*)d_in[0];
    const float* cond  = (const float*)d_in[1];
    const float* lnx_g = (const float*)d_in[2];
    const float* lnx_b = (const float*)d_in[3];
    const float* lnc_g = (const float*)d_in[4];
    const float* lnc_b = (const float*)d_in[5];
    const float* Wq    = (const float*)d_in[6];
    const float* Wk    = (const float*)d_in[7];
    const float* Wv    = (const float*)d_in[8];
    const float* Wo    = (const float*)d_in[9];
    const float* bo    = (const float*)d_in[10];
    const float* lnf_g = (const float*)d_in[11];
    const float* lnf_b = (const float*)d_in[12];
    float* out = (float*)d_out;
    char* ws = (char*)d_ws;

    const int R = BB * NN;  // 8192

    // workspace layout (bytes, 16B-aligned)
    short* xn_bf  = (short*)(ws);                    //  8 MB
    short* cn_bf  = (short*)(ws + (8u << 20));       // 12 MB
    short* Wq_t   = (short*)(ws + (20u << 20));      // 0.5 MB
    short* Wo_t   = (short*)(ws + (21u << 20));      // 0.5 MB
    short* Wkv_t  = (short*)(ws + (22u << 20));      // 1.5 MB
    short* qb     = (short*)(ws + (24u << 20));      //  8 MB
    short* kvb    = (short*)(ws + (32u << 20));      // 16 MB
    short* ab     = (short*)(ws + (48u << 20));      //  8 MB
    short* ob     = (short*)(ws + (56u << 20));      //  8 MB

    // fused LN(x)+LN(cond)+all weight transposes (one launch)
    prep_k<<<17664, 256, 0, stream>>>(
        x, cond, lnx_g, lnx_b, lnc_g, lnc_b, xn_bf, cn_bf,
        Wq, Wk, Wv, Wo, Wq_t, Wkv_t, Wo_t);

    // q = (xn @ Wq)*0.125*log2e ; [k|v] = cn @ [Wk|Wv]
    qkv_gemm<<<dim3(12, R / 128), 256, 0, stream>>>(
        xn_bf, cn_bf, Wq_t, Wkv_t, qb, kvb, 0.125f * 1.44269504089f);

    attention_mfma<<<dim3(NN / QT, NH, BB), 512, 0, stream>>>(qb, kvb, ab);

    // o-proj: bf16 out + bias (residual folded into the final LN)
    oproj_gemm<<<dim3(INNER / 64, R / 128), 256, 0, stream>>>(ab, Wo_t, ob, bo);

    layernorm_res_f32<<<R, 256, 0, stream>>>(ob, x, lnf_g, lnf_b, out);
}